// Round 2
// baseline (3260.818 us; speedup 1.0000x reference)
//
#include <hip/hip_runtime.h>
#include <hip/hip_fp16.h>
#include <math.h>

// Problem constants
#define NXg 128
#define NYg 128
#define Pg  (NXg*NYg)      // 16384 pixels
#define Bq  64             // batch
#define Wd  64             // WIDTH (channels)
#define NKX 24             // kept kx rows: 0..11 and 116..127
#define NMODE (NKX*12)     // 288
#define PI2_128 0.04908738521234052f   // 2*pi/128

// ---------------- workspace layout ----------------
// fp32 region (float offsets):
#define OFF_T1C 0
#define OFF_T1S 1536
#define OFF_T2C 3072
#define OFF_T2S 6144
#define OFF_VAL 9216
#define OFF_CNT (OFF_VAL + Bq*Pg)              // 1,057,792
#define OFF_XFR (OFF_CNT + Bq*Pg)              // 2,106,368
#define OFF_XFI (OFF_XFR + Bq*Wd*NMODE)        // 3,286,016
#define OFF_OFR (OFF_XFI + Bq*Wd*NMODE)        // 4,465,664
#define OFF_OFI (OFF_OFR + Bq*Wd*NMODE)        // 5,645,312
#define F32_END (OFF_OFI + Bq*Wd*NMODE)        // 6,824,960 floats = 27,299,840 B
// then fp16 activation tensor x: Bq*Wd*Pg halves = 134,217,728 B
// total ~154 MiB

// ---------------- twiddle tables ----------------
__global__ void k_tables(float* T1c, float* T1s, float* T2c, float* T2s) {
    int t = blockIdx.x * blockDim.x + threadIdx.x;
    if (t < 12*128) {
        int ky = t >> 7, y = t & 127;
        int m = (ky * y) & 127;
        float th = (float)m * PI2_128;
        T1c[t] = cosf(th);
        T1s[t] = sinf(th);
    } else if (t < 12*128 + 24*128) {
        int u = t - 12*128;
        int kxi = u >> 7, xx = u & 127;
        int kx = (kxi < 12) ? kxi : (104 + kxi);   // 116..127
        int m = (kx * xx) & 127;
        float th = (float)m * PI2_128;
        T2c[u] = cosf(th);
        T2s[u] = sinf(th);
    }
}

// ---------------- sparse scatter ----------------
__global__ void k_scatter(const float* __restrict__ xyt, const float* __restrict__ obs_c,
                          const float* __restrict__ obs_v, const int* __restrict__ nb,
                          const int* __restrict__ siy, const int* __restrict__ six,
                          float* val, float* cnt) {
    int t = blockIdx.x * 64 + threadIdx.x;   // 4096 = B*K
    int b = t >> 6;
    int id = nb[t];
    int sid = id / 50;                       // NT = 50
    float tq = xyt[b*3 + 2];
    float w = expf(-0.1f * fabsf(obs_c[id*3 + 2] - tq));
    int lin = siy[sid] * NYg + six[sid];
    atomicAdd(&val[b*Pg + lin], obs_v[id] * w);
    atomicAdd(&cnt[b*Pg + lin], w);
}

// ---------------- grid + fc0 (writes fp16 activations) ----------------
__global__ __launch_bounds__(256) void k_fc0(const float* __restrict__ val, const float* __restrict__ cnt,
                      const float* __restrict__ xg, const float* __restrict__ yg,
                      const float* __restrict__ w, const float* __restrict__ bb,
                      __half* __restrict__ x) {
    int t = blockIdx.x * 256 + threadIdx.x;  // Bq*Pg
    int b = t >> 14, p = t & (Pg-1);
    float c = cnt[t];
    float g = (c > 0.f) ? val[t] / fmaxf(c, 1e-6f) : 0.f;
    float a1 = xg[p], a2 = yg[p];
    __half* xb = x + (size_t)b * Wd * Pg + p;
    #pragma unroll 4
    for (int wc = 0; wc < Wd; wc++)
        xb[(size_t)wc * Pg] = __float2half(g * w[wc] + a1 * w[64 + wc] + a2 * w[128 + wc] + bb[wc]);
}

// ---------------- S12: fused forward partial-DFT (y then x) ----------------
// grid: Bq*Wd blocks, block 256. One (b,c) image per block.
__global__ __launch_bounds__(256) void k_s12(const __half* __restrict__ x,
                    const float* __restrict__ T1c, const float* __restrict__ T1s,
                    const float* __restrict__ T2c, const float* __restrict__ T2s,
                    float* __restrict__ xfr, float* __restrict__ xfi) {
    __shared__ __half xs[128][130];            // [xx][y], pad 2 halves
    __shared__ float yr[12][129], yi[12][129];
    int bc = blockIdx.x;
    const __half2* xp2 = (const __half2*)(x + (size_t)bc * Pg);
    for (int i = threadIdx.x; i < Pg/2; i += 256) {
        __half2 v = xp2[i];
        int xx = i >> 6, y2 = (i & 63) << 1;
        xs[xx][y2]   = v.x;
        xs[xx][y2+1] = v.y;
    }
    __syncthreads();
    // stage A: y-DFT, ky = 0..11  (e^{-i 2pi ky y /128})
    for (int u = threadIdx.x; u < 12*128; u += 256) {
        int ky = u >> 7, xx = u & 127;
        const float* c = T1c + (ky << 7);
        const float* s = T1s + (ky << 7);
        float sr = 0.f, si = 0.f;
        #pragma unroll 8
        for (int y = 0; y < 128; y++) {
            float v = __half2float(xs[xx][y]);
            sr = fmaf(v, c[y], sr);
            si = fmaf(-v, s[y], si);
        }
        yr[ky][xx] = sr;
        yi[ky][xx] = si;
    }
    __syncthreads();
    // stage B: x-DFT, keep 24 kx rows
    for (int o = threadIdx.x; o < NMODE; o += 256) {
        int kxi = o / 12, ky = o - kxi*12;
        const float* c = T2c + (kxi << 7);
        const float* s = T2s + (kxi << 7);
        float sr = 0.f, si = 0.f;
        #pragma unroll 8
        for (int xx = 0; xx < 128; xx++) {
            float a = yr[ky][xx], b = yi[ky][xx];
            float cc = c[xx], ss = s[xx];
            sr += a*cc + b*ss;     // (a+ib)(cc - i ss)
            si += b*cc - a*ss;
        }
        xfr[(size_t)bc * NMODE + o] = sr;
        xfi[(size_t)bc * NMODE + o] = si;
    }
}

// ---------------- S3: mode mixing (complex 64ch -> 64ch) ----------------
// grid: (Bq, 24), block 256
__global__ __launch_bounds__(256) void k_s3(const float* __restrict__ xfr, const float* __restrict__ xfi,
                    const float* __restrict__ w1r, const float* __restrict__ w1i,
                    const float* __restrict__ w2r, const float* __restrict__ w2i,
                    float* __restrict__ ofr, float* __restrict__ ofi, int layer) {
    __shared__ float ar[64][12], ai[64][12];
    int b = blockIdx.x, kxi = blockIdx.y;
    for (int i = threadIdx.x; i < 64*12; i += 256) {
        int ii = i / 12, ky = i - ii*12;
        size_t idx = (size_t)(b*64 + ii) * NMODE + kxi*12 + ky;
        ar[ii][ky] = xfr[idx];
        ai[ii][ky] = xfi[idx];
    }
    __syncthreads();
    const float *wr, *wi; int kxw;
    if (kxi < 12) { wr = w1r; wi = w1i; kxw = kxi; }
    else          { wr = w2r; wi = w2i; kxw = kxi - 12; }
    size_t lbase = (size_t)layer * 64*64*144 + (size_t)kxw*12;
    for (int o = threadIdx.x; o < 64*12; o += 256) {
        int oo = o / 12, ky = o - oo*12;
        float sr = 0.f, si = 0.f;
        #pragma unroll 4
        for (int i2 = 0; i2 < 64; i2++) {
            float xr = ar[i2][ky], xi2 = ai[i2][ky];
            size_t widx = lbase + (size_t)(i2*64 + oo)*144 + ky;
            float wrr = wr[widx], wii = wi[widx];
            sr += xr*wrr - xi2*wii;
            si += xr*wii + xi2*wrr;
        }
        size_t oidx = (size_t)(b*64 + oo) * NMODE + kxi*12 + ky;
        ofr[oidx] = sr;
        ofi[oidx] = si;
    }
}

// ---------------- S45: fused inverse-x + inverse-y + pointwise + gelu ----------------
// grid: (NXg rows, Bq), block 256. In-place update of x (each block owns its row).
__global__ __launch_bounds__(256) void k_s45(__half* __restrict__ x,
                    const float* __restrict__ ofr, const float* __restrict__ ofi,
                    const float* __restrict__ T1c, const float* __restrict__ T1s,
                    const float* __restrict__ T2c, const float* __restrict__ T2s,
                    const float* __restrict__ pw, const float* __restrict__ pwb, int layer) {
    __shared__ float xsf[64][129];     // activations [c][y] at this row
    __shared__ float pws[64][64];
    __shared__ float gr[64][12], gi[64][12];
    __shared__ float t2r[24], t2i[24];
    int row = blockIdx.x, b = blockIdx.y;
    __half* xb = x + (size_t)b * Wd * Pg + row * 128;
    for (int i = threadIdx.x; i < 64*64; i += 256) {
        int c = i >> 6, j = i & 63;
        const __half2* p = (const __half2*)(xb + (size_t)c * Pg);
        __half2 v = p[j];
        xsf[c][2*j]   = __half2float(v.x);
        xsf[c][2*j+1] = __half2float(v.y);
    }
    for (int i = threadIdx.x; i < 4096; i += 256)
        pws[i >> 6][i & 63] = pw[(size_t)layer * 4096 + i];
    if (threadIdx.x < 24) {
        t2r[threadIdx.x] = T2c[threadIdx.x * 128 + row];
        t2i[threadIdx.x] = T2s[threadIdx.x * 128 + row];
    }
    __syncthreads();
    // inverse-x at x-position `row`: g[o][ky] = sum_kx of[o,kx,ky] e^{+i 2pi kx row/128}
    for (int i = threadIdx.x; i < 768; i += 256) {
        int o = i / 12, ky = i - o*12;
        const float* pr = ofr + (size_t)(b*64 + o) * NMODE + ky;
        const float* pi = ofi + (size_t)(b*64 + o) * NMODE + ky;
        float sr = 0.f, si = 0.f;
        #pragma unroll
        for (int k = 0; k < 24; k++) {
            float a = pr[k*12], bb = pi[k*12];
            float cc = t2r[k], ss = t2i[k];
            sr += a*cc - bb*ss;
            si += a*ss + bb*cc;
        }
        gr[o][ky] = sr;
        gi[o][ky] = si;
    }
    __syncthreads();
    int y = threadIdx.x & 127;
    int ohalf = threadIdx.x >> 7;
    float c1[11], s1[11];
    #pragma unroll
    for (int ky = 1; ky < 12; ky++) {
        c1[ky-1] = T1c[ky*128 + y];
        s1[ky-1] = T1s[ky*128 + y];
    }
    for (int it = 0; it < 32; it++) {
        int o = (it << 1) + ohalf;
        float s = 0.f;
        #pragma unroll 8
        for (int c = 0; c < 64; c++) s = fmaf(pws[o][c], xsf[c][y], s);
        float sp = gr[o][0];   // ky=0: imag ignored (irfft semantics)
        #pragma unroll
        for (int ky = 1; ky < 12; ky++)
            sp += 2.f * (gr[o][ky]*c1[ky-1] - gi[o][ky]*s1[ky-1]);
        float v = sp * (1.f/16384.f) + s + pwb[layer*64 + o];
        float g = 0.5f * v * (1.f + erff(v * 0.70710678118654752f));
        xb[(size_t)o * Pg + y] = __float2half(g);
    }
}

// ---------------- final: layer-3 at 4 points + fc1 + fc2 + bilinear ----------------
// grid: Bq, block 256 (tid -> point=tid>>6, o=tid&63)
__global__ __launch_bounds__(256) void k_final(const __half* __restrict__ x,
                    const float* __restrict__ ofr, const float* __restrict__ ofi,
                    const float* __restrict__ pw, const float* __restrict__ pwb,
                    const float* __restrict__ fc1w, const float* __restrict__ fc1b,
                    const float* __restrict__ fc2w, const float* __restrict__ fc2b,
                    const float* __restrict__ xyt, const int* __restrict__ Lx, const int* __restrict__ Ly,
                    float* __restrict__ out) {
    __shared__ float y4[4][64];
    __shared__ float hh[4][129];
    __shared__ int   pxy[4][2];
    __shared__ float wxy[2];
    int b = blockIdx.x;
    if (threadIdx.x == 0) {
        float Lxf = fmaxf((float)Lx[0], 1e-6f);
        float Lyf = fmaxf((float)Ly[0], 1e-6f);
        float x01 = fminf(fmaxf(xyt[b*3 + 0] / Lxf, 0.f), 1.f);
        float y01 = fminf(fmaxf(xyt[b*3 + 1] / Lyf, 0.f), 1.f);
        float gx = x01 * (NXg - 1), gy = y01 * (NYg - 1);
        int x0 = (int)floorf(gx), y0 = (int)floorf(gy);
        int x1 = min(x0 + 1, NXg - 1), y1 = min(y0 + 1, NYg - 1);
        wxy[0] = gx - (float)x0;
        wxy[1] = gy - (float)y0;
        pxy[0][0] = x0; pxy[0][1] = y0;
        pxy[1][0] = x1; pxy[1][1] = y0;
        pxy[2][0] = x0; pxy[2][1] = y1;
        pxy[3][0] = x1; pxy[3][1] = y1;
    }
    __syncthreads();
    {
        int p = threadIdx.x >> 6, o = threadIdx.x & 63;
        int px = pxy[p][0], py = pxy[p][1];
        float gkr[12], gki[12];
        #pragma unroll
        for (int ky = 0; ky < 12; ky++) { gkr[ky] = 0.f; gki[ky] = 0.f; }
        const float* obr = ofr + (size_t)(b*64 + o) * NMODE;
        const float* obi = ofi + (size_t)(b*64 + o) * NMODE;
        for (int kxi = 0; kxi < 24; kxi++) {
            int kx = (kxi < 12) ? kxi : (104 + kxi);
            int m = (kx * px) & 127;
            float th = (float)m * PI2_128;
            float ss, cc; sincosf(th, &ss, &cc);
            #pragma unroll
            for (int ky = 0; ky < 12; ky++) {
                float a = obr[kxi*12 + ky], bb = obi[kxi*12 + ky];
                gkr[ky] += a*cc - bb*ss;
                gki[ky] += a*ss + bb*cc;
            }
        }
        float sp = gkr[0];
        #pragma unroll
        for (int ky = 1; ky < 12; ky++) {
            int m = (ky * py) & 127;
            float th = (float)m * PI2_128;
            float ss, cc; sincosf(th, &ss, &cc);
            sp += 2.f * (gkr[ky]*cc - gki[ky]*ss);
        }
        float s = 0.f;
        const __half* xb = x + (size_t)b * Wd * Pg + px*128 + py;
        #pragma unroll 4
        for (int c = 0; c < 64; c++)
            s += pw[3*4096 + o*64 + c] * __half2float(xb[(size_t)c * Pg]);
        y4[p][o] = sp * (1.f/16384.f) + s + pwb[3*64 + o];
    }
    __syncthreads();
    for (int i = threadIdx.x; i < 512; i += 256) {
        int p = i >> 7, f = i & 127;
        float s = fc1b[f];
        #pragma unroll 4
        for (int w = 0; w < 64; w++) s += y4[p][w] * fc1w[w*128 + f];
        hh[p][f] = 0.5f * s * (1.f + erff(s * 0.70710678118654752f));
    }
    __syncthreads();
    if (threadIdx.x < 3) {
        int o3 = threadIdx.x;
        float f4[4];
        #pragma unroll
        for (int p = 0; p < 4; p++) {
            float s = fc2b[o3];
            #pragma unroll 4
            for (int f = 0; f < 128; f++) s += hh[p][f] * fc2w[f*3 + o3];
            f4[p] = s;
        }
        float wx = wxy[0], wy = wxy[1];
        float top = f4[0]*(1.f - wx) + f4[1]*wx;
        float bot = f4[2]*(1.f - wx) + f4[3]*wx;
        out[b*3 + o3] = top*(1.f - wy) + bot*wy;
    }
}

extern "C" void kernel_launch(void* const* d_in, const int* in_sizes, int n_in,
                              void* d_out, int out_size, void* d_ws, size_t ws_size,
                              hipStream_t stream) {
    const float* xyt    = (const float*)d_in[0];
    const float* obs_c  = (const float*)d_in[1];
    const float* obs_v  = (const float*)d_in[2];
    const float* xg     = (const float*)d_in[3];
    const float* yg     = (const float*)d_in[4];
    const float* fc0w   = (const float*)d_in[5];
    const float* fc0b   = (const float*)d_in[6];
    const float* w1r    = (const float*)d_in[7];
    const float* w1i    = (const float*)d_in[8];
    const float* w2r    = (const float*)d_in[9];
    const float* w2i    = (const float*)d_in[10];
    const float* pww    = (const float*)d_in[11];
    const float* pwb    = (const float*)d_in[12];
    const float* fc1w   = (const float*)d_in[13];
    const float* fc1b   = (const float*)d_in[14];
    const float* fc2w   = (const float*)d_in[15];
    const float* fc2b   = (const float*)d_in[16];
    const int*   nb     = (const int*)d_in[17];
    const int*   siy    = (const int*)d_in[18];
    const int*   six    = (const int*)d_in[19];
    const int*   Lx     = (const int*)d_in[20];
    const int*   Ly     = (const int*)d_in[21];
    float* out = (float*)d_out;

    float* W = (float*)d_ws;
    float* T1c = W + OFF_T1C;
    float* T1s = W + OFF_T1S;
    float* T2c = W + OFF_T2C;
    float* T2s = W + OFF_T2S;
    float* val = W + OFF_VAL;
    float* cnt = W + OFF_CNT;
    float* xfr = W + OFF_XFR;
    float* xfi = W + OFF_XFI;
    float* ofr = W + OFF_OFR;
    float* ofi = W + OFF_OFI;
    __half* xh = (__half*)(W + F32_END);   // 128 MB fp16 activations

    // zero scatter accumulators (val+cnt contiguous)
    hipMemsetAsync(val, 0, (size_t)2 * Bq * Pg * sizeof(float), stream);

    k_tables<<<18, 256, 0, stream>>>(T1c, T1s, T2c, T2s);
    k_scatter<<<64, 64, 0, stream>>>(xyt, obs_c, obs_v, nb, siy, six, val, cnt);
    k_fc0<<<(Bq*Pg)/256, 256, 0, stream>>>(val, cnt, xg, yg, fc0w, fc0b, xh);

    for (int l = 0; l < 3; l++) {
        k_s12<<<Bq*Wd, 256, 0, stream>>>(xh, T1c, T1s, T2c, T2s, xfr, xfi);
        k_s3<<<dim3(Bq, 24), 256, 0, stream>>>(xfr, xfi, w1r, w1i, w2r, w2i, ofr, ofi, l);
        k_s45<<<dim3(NXg, Bq), 256, 0, stream>>>(xh, ofr, ofi, T1c, T1s, T2c, T2s, pww, pwb, l);
    }
    // layer 3: forward transform + mode mix only; evaluate at 4 points in k_final
    k_s12<<<Bq*Wd, 256, 0, stream>>>(xh, T1c, T1s, T2c, T2s, xfr, xfi);
    k_s3<<<dim3(Bq, 24), 256, 0, stream>>>(xfr, xfi, w1r, w1i, w2r, w2i, ofr, ofi, 3);
    k_final<<<Bq, 256, 0, stream>>>(xh, ofr, ofi, pww, pwb, fc1w, fc1b, fc2w, fc2b,
                                    xyt, Lx, Ly, out);
}

// Round 3
// 1056.963 us; speedup vs baseline: 3.0851x; 3.0851x over previous
//
#include <hip/hip_runtime.h>
#include <math.h>

// Problem constants
#define NXg 128
#define NYg 128
#define Pg  (NXg*NYg)      // 16384 pixels
#define Bq  64             // batch
#define Wd  64             // WIDTH (channels)
#define NKX 24             // kept kx rows: 0..11 and 116..127
#define NMODE (NKX*12)     // 288
#define PI2_128 0.04908738521234052f   // 2*pi/128

typedef _Float16 f16x8 __attribute__((ext_vector_type(8)));
typedef float    f32x4 __attribute__((ext_vector_type(4)));

// ---------------- workspace layout ----------------
// fp32 region (float offsets):
#define OFF_T2C 0
#define OFF_T2S (OFF_T2C + 24*128)
#define OFF_VAL (OFF_T2S + 24*128)
#define OFF_CNT (OFF_VAL + Bq*Pg)
#define OFF_XFR (OFF_CNT + Bq*Pg)
#define OFF_XFI (OFF_XFR + Bq*Wd*NMODE)
#define OFF_OFR (OFF_XFI + Bq*Wd*NMODE)
#define OFF_OFI (OFF_OFR + Bq*Wd*NMODE)
#define F32_END (OFF_OFI + Bq*Wd*NMODE)
// fp16 region (half offsets from (W + F32_END)):
//   T1e_g: 32*128   (rows 0..11 cos(ky*y), 12..23 -sin(ky*y), 24..31 zero)
//   A2_g:  48*256   (stage-B DFT matrix)
//   xh:    Bq*Wd*Pg activations
#define H_T1E 0
#define H_A2  (H_T1E + 32*128)
#define H_X   (H_A2 + 48*256)

// ---------------- twiddle tables ----------------
__global__ void k_tables(float* T2c, float* T2s, _Float16* T1e_g, _Float16* A2_g) {
    int t = blockIdx.x * blockDim.x + threadIdx.x;   // 0..12287
    if (t < 24*128) {
        int kxi = t >> 7, xx = t & 127;
        int kx = (kxi < 12) ? kxi : (104 + kxi);   // 116..127
        float th = (float)((kx * xx) & 127) * PI2_128;
        T2c[t] = cosf(th);
        T2s[t] = sinf(th);
    }
    if (t < 32*128) {
        int r = t >> 7, y = t & 127;
        float v = 0.f;
        if (r < 12)      v =  cosf((float)((r * y) & 127) * PI2_128);
        else if (r < 24) v = -sinf((float)(((r-12) * y) & 127) * PI2_128);
        T1e_g[t] = (_Float16)v;
    }
    if (t < 48*256) {
        int m = t >> 8, k = t & 255;
        int x = k & 127;
        int hi = (k >= 128);
        float v;
        if (m < 24) {
            int kx = (m < 12) ? m : (104 + m);
            float th = (float)((kx * x) & 127) * PI2_128;
            v = hi ? sinf(th) : cosf(th);
        } else {
            int mm = m - 24;
            int kx = (mm < 12) ? mm : (104 + mm);
            float th = (float)((kx * x) & 127) * PI2_128;
            v = hi ? cosf(th) : -sinf(th);
        }
        A2_g[t] = (_Float16)v;
    }
}

// ---------------- sparse scatter ----------------
__global__ void k_scatter(const float* __restrict__ xyt, const float* __restrict__ obs_c,
                          const float* __restrict__ obs_v, const int* __restrict__ nb,
                          const int* __restrict__ siy, const int* __restrict__ six,
                          float* val, float* cnt) {
    int t = blockIdx.x * 64 + threadIdx.x;   // 4096 = B*K
    int b = t >> 6;
    int id = nb[t];
    int sid = id / 50;                       // NT = 50
    float tq = xyt[b*3 + 2];
    float w = expf(-0.1f * fabsf(obs_c[id*3 + 2] - tq));
    int lin = siy[sid] * NYg + six[sid];
    atomicAdd(&val[b*Pg + lin], obs_v[id] * w);
    atomicAdd(&cnt[b*Pg + lin], w);
}

// ---------------- grid + fc0 (writes fp16 activations) ----------------
__global__ __launch_bounds__(256) void k_fc0(const float* __restrict__ val, const float* __restrict__ cnt,
                      const float* __restrict__ xg, const float* __restrict__ yg,
                      const float* __restrict__ w, const float* __restrict__ bb,
                      _Float16* __restrict__ x) {
    int t = blockIdx.x * 256 + threadIdx.x;  // Bq*Pg
    int b = t >> 14, p = t & (Pg-1);
    float c = cnt[t];
    float g = (c > 0.f) ? val[t] / fmaxf(c, 1e-6f) : 0.f;
    float a1 = xg[p], a2 = yg[p];
    _Float16* xb = x + (size_t)b * Wd * Pg + p;
    #pragma unroll 4
    for (int wc = 0; wc < Wd; wc++)
        xb[(size_t)wc * Pg] = (_Float16)(g * w[wc] + a1 * w[64 + wc] + a2 * w[128 + wc] + bb[wc]);
}

// ---------------- S12: fused forward partial-DFT via MFMA ----------------
// grid: Bq*Wd blocks, block 256 (4 waves). One (b,c) image per block.
// Stage A: Y(32x128) = T1e(32x128_y) @ X^T   (K=128 over y)
// Stage B: XF(48x12) = A2(48x256) @ [Yr;Yi]  (K=256)
__global__ __launch_bounds__(256) void k_s12(const _Float16* __restrict__ x,
                    const _Float16* __restrict__ T1e_g, const _Float16* __restrict__ A2_g,
                    float* __restrict__ xfr, float* __restrict__ xfi) {
    __shared__ __align__(16) char smem[34816 + 8704 + 8704];
    _Float16 (*Xs)[136]  = (_Float16(*)[136])smem;             // [xx][y], reused as A2
    _Float16 (*A2)[264]  = (_Float16(*)[264])smem;
    _Float16 (*T1e)[136] = (_Float16(*)[136])(smem + 34816);
    _Float16 (*Y)[136]   = (_Float16(*)[136])(smem + 34816 + 8704); // [32 rows][x]

    int bc = blockIdx.x;
    int tid = threadIdx.x;
    int wave = tid >> 6, lane = tid & 63;
    int l15 = lane & 15, quad = lane >> 4;

    // fill Xs: 2048 float4 (16 halves per row-chunk of 8)
    const float4* xp4 = (const float4*)(x + (size_t)bc * Pg);
    for (int i = tid; i < 2048; i += 256) {
        int xx = i >> 4, seg = i & 15;
        *(float4*)&Xs[xx][seg * 8] = xp4[i];
    }
    // fill T1e: 512 float4
    const float4* t1p = (const float4*)T1e_g;
    for (int i = tid; i < 512; i += 256) {
        int r = i >> 4, seg = i & 15;
        *(float4*)&T1e[r][seg * 8] = t1p[i];
    }
    __syncthreads();

    // ---- stage A ----
    f16x8 afr[2][4];
    #pragma unroll
    for (int mt = 0; mt < 2; mt++)
        #pragma unroll
        for (int q = 0; q < 4; q++)
            afr[mt][q] = *(const f16x8*)&T1e[mt*16 + l15][q*32 + quad*8];
    #pragma unroll
    for (int ntl = 0; ntl < 2; ntl++) {
        int nt = wave*2 + ntl;
        f32x4 acc0 = {0.f,0.f,0.f,0.f}, acc1 = {0.f,0.f,0.f,0.f};
        #pragma unroll
        for (int q = 0; q < 4; q++) {
            f16x8 b = *(const f16x8*)&Xs[nt*16 + l15][q*32 + quad*8];
            acc0 = __builtin_amdgcn_mfma_f32_16x16x32_f16(afr[0][q], b, acc0, 0, 0, 0);
            acc1 = __builtin_amdgcn_mfma_f32_16x16x32_f16(afr[1][q], b, acc1, 0, 0, 0);
        }
        __syncthreads();   // ensure all stage-A reads of Xs done before... (first ntl only matters for A2 overwrite later; keep one sync below instead)
        #pragma unroll
        for (int r = 0; r < 4; r++) {
            Y[quad*4 + r][nt*16 + l15]      = (_Float16)acc0[r];
            Y[16 + quad*4 + r][nt*16 + l15] = (_Float16)acc1[r];
        }
    }
    __syncthreads();

    // fill A2 (overwrites Xs region): 1536 float4
    const float4* a2p = (const float4*)A2_g;
    for (int i = tid; i < 1536; i += 256) {
        int r = i >> 5, seg = i & 31;
        *(float4*)&A2[r][seg * 8] = a2p[i];
    }
    __syncthreads();

    // ---- stage B ----
    if (wave < 3) {
        f32x4 acc = {0.f,0.f,0.f,0.f};
        #pragma unroll
        for (int q = 0; q < 8; q++) {
            f16x8 a = *(const f16x8*)&A2[wave*16 + l15][q*32 + quad*8];
            const _Float16* brow = (q < 4) ? &Y[l15][q*32 + quad*8]
                                           : &Y[12 + l15][(q-4)*32 + quad*8];
            f16x8 b = *(const f16x8*)brow;
            acc = __builtin_amdgcn_mfma_f32_16x16x32_f16(a, b, acc, 0, 0, 0);
        }
        if (l15 < 12) {
            #pragma unroll
            for (int r = 0; r < 4; r++) {
                int m = wave*16 + quad*4 + r;
                if (m < 24) xfr[(size_t)bc * NMODE + m*12 + l15] = acc[r];
                else        xfi[(size_t)bc * NMODE + (m-24)*12 + l15] = acc[r];
            }
        }
    }
}

// ---------------- S3: mode mixing (complex 64ch -> 64ch), fp32 VALU ----------------
// grid: (Bq, 24), block 256
__global__ __launch_bounds__(256) void k_s3(const float* __restrict__ xfr, const float* __restrict__ xfi,
                    const float* __restrict__ w1r, const float* __restrict__ w1i,
                    const float* __restrict__ w2r, const float* __restrict__ w2i,
                    float* __restrict__ ofr, float* __restrict__ ofi, int layer) {
    __shared__ float ar[64][12], ai[64][12];
    int b = blockIdx.x, kxi = blockIdx.y;
    for (int i = threadIdx.x; i < 64*12; i += 256) {
        int ii = i / 12, ky = i - ii*12;
        size_t idx = (size_t)(b*64 + ii) * NMODE + kxi*12 + ky;
        ar[ii][ky] = xfr[idx];
        ai[ii][ky] = xfi[idx];
    }
    __syncthreads();
    const float *wr, *wi; int kxw;
    if (kxi < 12) { wr = w1r; wi = w1i; kxw = kxi; }
    else          { wr = w2r; wi = w2i; kxw = kxi - 12; }
    size_t lbase = (size_t)layer * 64*64*144 + (size_t)kxw*12;
    for (int o = threadIdx.x; o < 64*12; o += 256) {
        int oo = o / 12, ky = o - oo*12;
        float sr = 0.f, si = 0.f;
        #pragma unroll 4
        for (int i2 = 0; i2 < 64; i2++) {
            float xr = ar[i2][ky], xi2 = ai[i2][ky];
            size_t widx = lbase + (size_t)(i2*64 + oo)*144 + ky;
            float wrr = wr[widx], wii = wi[widx];
            sr += xr*wrr - xi2*wii;
            si += xr*wii + xi2*wrr;
        }
        size_t oidx = (size_t)(b*64 + oo) * NMODE + kxi*12 + ky;
        ofr[oidx] = sr;
        ofi[oidx] = si;
    }
}

// ---------------- S45: inverse-x (VALU) + fused [pointwise | inverse-y] MFMA + gelu ----
// grid: (NXg rows, Bq), block 256 (4 waves). In-place update of x.
// GEMM: out(64 o x 128 y) = A(64 x 96) @ B(96 x 128)
//   A = [W(64x64) | Gr*sc(64x12) | Gi*sc(64x12) | 0(64x8)]
//   B = [X(64x128); cos_ky(12x128); -sin_ky(12x128); 0(8x128)]
__global__ __launch_bounds__(256) void k_s45(_Float16* __restrict__ x,
                    const float* __restrict__ ofr, const float* __restrict__ ofi,
                    const _Float16* __restrict__ T1e_g,
                    const float* __restrict__ T2c, const float* __restrict__ T2s,
                    const float* __restrict__ pw, const float* __restrict__ pwb, int layer) {
    __shared__ _Float16 BsT[128][104];   // [y][k]  k: 0..63 X, 64..95 spectral rows
    __shared__ _Float16 As[64][104];     // [o][k]  k: 0..63 W, 64..87 G, 88..95 zero
    __shared__ float t2r[24], t2i[24];
    int row = blockIdx.x, b = blockIdx.y;
    int tid = threadIdx.x;
    int wave = tid >> 6, lane = tid & 63;
    int l15 = lane & 15, quad = lane >> 4;

    _Float16* xb = x + (size_t)b * Wd * Pg + row * 128;

    // X -> BsT transposed
    for (int i = tid; i < 4096; i += 256) {
        int c = i >> 6, j = i & 63;
        f16x8 dummy; (void)dummy;
        const _Float16* src = xb + (size_t)c * Pg + 2*j;
        _Float16 v0 = src[0], v1 = src[1];
        BsT[2*j][c]   = v0;
        BsT[2*j+1][c] = v1;
    }
    // spectral basis rows (incl. zero rows 24..31)
    for (int i = tid; i < 4096; i += 256) {
        int t = i >> 7, y = i & 127;
        BsT[y][64 + t] = T1e_g[t*128 + y];
    }
    // W -> As
    for (int i = tid; i < 4096; i += 256)
        As[i >> 6][i & 63] = (_Float16)pw[(size_t)layer * 4096 + i];
    // zero pad cols 88..95
    for (int i = tid; i < 512; i += 256)
        As[i >> 3][88 + (i & 7)] = (_Float16)0.f;
    if (tid < 24) {
        t2r[tid] = T2c[tid * 128 + row];
        t2i[tid] = T2s[tid * 128 + row];
    }
    __syncthreads();

    // inverse-x at x=row: G[o][ky] = sum_kx of[o,kx,ky] * e^{+i 2pi kx row/128}
    for (int i = tid; i < 768; i += 256) {
        int o = i / 12, ky = i - o*12;
        const float* pr = ofr + (size_t)(b*64 + o) * NMODE + ky;
        const float* pi = ofi + (size_t)(b*64 + o) * NMODE + ky;
        float sr = 0.f, si = 0.f;
        #pragma unroll
        for (int k = 0; k < 24; k++) {
            float a = pr[k*12], bb = pi[k*12];
            float cc = t2r[k], ss = t2i[k];
            sr += a*cc - bb*ss;
            si += a*ss + bb*cc;
        }
        float sc = ((ky == 0) ? 1.f : 2.f) * (1.f/16384.f);
        As[o][64 + ky] = (_Float16)(sr * sc);
        As[o][76 + ky] = (_Float16)(si * sc);
    }
    __syncthreads();

    // MFMA: wave w -> o-tile w (rows w*16..w*16+15), all 8 y-tiles
    f16x8 afr[3];
    #pragma unroll
    for (int q = 0; q < 3; q++)
        afr[q] = *(const f16x8*)&As[wave*16 + l15][q*32 + quad*8];
    float pb[4];
    #pragma unroll
    for (int r = 0; r < 4; r++)
        pb[r] = pwb[layer*64 + wave*16 + quad*4 + r];
    for (int nt = 0; nt < 8; nt++) {
        f32x4 acc = {0.f,0.f,0.f,0.f};
        #pragma unroll
        for (int q = 0; q < 3; q++) {
            f16x8 bfr = *(const f16x8*)&BsT[nt*16 + l15][q*32 + quad*8];
            acc = __builtin_amdgcn_mfma_f32_16x16x32_f16(afr[q], bfr, acc, 0, 0, 0);
        }
        int y = nt*16 + l15;
        #pragma unroll
        for (int r = 0; r < 4; r++) {
            int o = wave*16 + quad*4 + r;
            float v = acc[r] + pb[r];
            float g = 0.5f * v * (1.f + erff(v * 0.70710678118654752f));
            xb[(size_t)o * Pg + y] = (_Float16)g;
        }
    }
}

// ---------------- final: layer-3 at 4 points + fc1 + fc2 + bilinear ----------------
// grid: Bq, block 256 (tid -> point=tid>>6, o=tid&63)
__global__ __launch_bounds__(256) void k_final(const _Float16* __restrict__ x,
                    const float* __restrict__ ofr, const float* __restrict__ ofi,
                    const float* __restrict__ pw, const float* __restrict__ pwb,
                    const float* __restrict__ fc1w, const float* __restrict__ fc1b,
                    const float* __restrict__ fc2w, const float* __restrict__ fc2b,
                    const float* __restrict__ xyt, const int* __restrict__ Lx, const int* __restrict__ Ly,
                    float* __restrict__ out) {
    __shared__ float y4[4][64];
    __shared__ float hh[4][129];
    __shared__ int   pxy[4][2];
    __shared__ float wxy[2];
    int b = blockIdx.x;
    if (threadIdx.x == 0) {
        float Lxf = fmaxf((float)Lx[0], 1e-6f);
        float Lyf = fmaxf((float)Ly[0], 1e-6f);
        float x01 = fminf(fmaxf(xyt[b*3 + 0] / Lxf, 0.f), 1.f);
        float y01 = fminf(fmaxf(xyt[b*3 + 1] / Lyf, 0.f), 1.f);
        float gx = x01 * (NXg - 1), gy = y01 * (NYg - 1);
        int x0 = (int)floorf(gx), y0 = (int)floorf(gy);
        int x1 = min(x0 + 1, NXg - 1), y1 = min(y0 + 1, NYg - 1);
        wxy[0] = gx - (float)x0;
        wxy[1] = gy - (float)y0;
        pxy[0][0] = x0; pxy[0][1] = y0;
        pxy[1][0] = x1; pxy[1][1] = y0;
        pxy[2][0] = x0; pxy[2][1] = y1;
        pxy[3][0] = x1; pxy[3][1] = y1;
    }
    __syncthreads();
    {
        int p = threadIdx.x >> 6, o = threadIdx.x & 63;
        int px = pxy[p][0], py = pxy[p][1];
        float gkr[12], gki[12];
        #pragma unroll
        for (int ky = 0; ky < 12; ky++) { gkr[ky] = 0.f; gki[ky] = 0.f; }
        const float* obr = ofr + (size_t)(b*64 + o) * NMODE;
        const float* obi = ofi + (size_t)(b*64 + o) * NMODE;
        for (int kxi = 0; kxi < 24; kxi++) {
            int kx = (kxi < 12) ? kxi : (104 + kxi);
            int m = (kx * px) & 127;
            float th = (float)m * PI2_128;
            float ss, cc; sincosf(th, &ss, &cc);
            #pragma unroll
            for (int ky = 0; ky < 12; ky++) {
                float a = obr[kxi*12 + ky], bb = obi[kxi*12 + ky];
                gkr[ky] += a*cc - bb*ss;
                gki[ky] += a*ss + bb*cc;
            }
        }
        float sp = gkr[0];
        #pragma unroll
        for (int ky = 1; ky < 12; ky++) {
            int m = (ky * py) & 127;
            float th = (float)m * PI2_128;
            float ss, cc; sincosf(th, &ss, &cc);
            sp += 2.f * (gkr[ky]*cc - gki[ky]*ss);
        }
        float s = 0.f;
        const _Float16* xb = x + (size_t)b * Wd * Pg + px*128 + py;
        #pragma unroll 4
        for (int c = 0; c < 64; c++)
            s += pw[3*4096 + o*64 + c] * (float)xb[(size_t)c * Pg];
        y4[p][o] = sp * (1.f/16384.f) + s + pwb[3*64 + o];
    }
    __syncthreads();
    for (int i = threadIdx.x; i < 512; i += 256) {
        int p = i >> 7, f = i & 127;
        float s = fc1b[f];
        #pragma unroll 4
        for (int w = 0; w < 64; w++) s += y4[p][w] * fc1w[w*128 + f];
        hh[p][f] = 0.5f * s * (1.f + erff(s * 0.70710678118654752f));
    }
    __syncthreads();
    if (threadIdx.x < 3) {
        int o3 = threadIdx.x;
        float f4[4];
        #pragma unroll
        for (int p = 0; p < 4; p++) {
            float s = fc2b[o3];
            #pragma unroll 4
            for (int f = 0; f < 128; f++) s += hh[p][f] * fc2w[f*3 + o3];
            f4[p] = s;
        }
        float wx = wxy[0], wy = wxy[1];
        float top = f4[0]*(1.f - wx) + f4[1]*wx;
        float bot = f4[2]*(1.f - wx) + f4[3]*wx;
        out[b*3 + o3] = top*(1.f - wy) + bot*wy;
    }
}

extern "C" void kernel_launch(void* const* d_in, const int* in_sizes, int n_in,
                              void* d_out, int out_size, void* d_ws, size_t ws_size,
                              hipStream_t stream) {
    const float* xyt    = (const float*)d_in[0];
    const float* obs_c  = (const float*)d_in[1];
    const float* obs_v  = (const float*)d_in[2];
    const float* xg     = (const float*)d_in[3];
    const float* yg     = (const float*)d_in[4];
    const float* fc0w   = (const float*)d_in[5];
    const float* fc0b   = (const float*)d_in[6];
    const float* w1r    = (const float*)d_in[7];
    const float* w1i    = (const float*)d_in[8];
    const float* w2r    = (const float*)d_in[9];
    const float* w2i    = (const float*)d_in[10];
    const float* pww    = (const float*)d_in[11];
    const float* pwb    = (const float*)d_in[12];
    const float* fc1w   = (const float*)d_in[13];
    const float* fc1b   = (const float*)d_in[14];
    const float* fc2w   = (const float*)d_in[15];
    const float* fc2b   = (const float*)d_in[16];
    const int*   nb     = (const int*)d_in[17];
    const int*   siy    = (const int*)d_in[18];
    const int*   six    = (const int*)d_in[19];
    const int*   Lx     = (const int*)d_in[20];
    const int*   Ly     = (const int*)d_in[21];
    float* out = (float*)d_out;

    float* W = (float*)d_ws;
    float* T2c = W + OFF_T2C;
    float* T2s = W + OFF_T2S;
    float* val = W + OFF_VAL;
    float* cnt = W + OFF_CNT;
    float* xfr = W + OFF_XFR;
    float* xfi = W + OFF_XFI;
    float* ofr = W + OFF_OFR;
    float* ofi = W + OFF_OFI;
    _Float16* Hbase = (_Float16*)(W + F32_END);
    _Float16* T1e_g = Hbase + H_T1E;
    _Float16* A2_g  = Hbase + H_A2;
    _Float16* xh    = Hbase + H_X;

    // zero scatter accumulators (val+cnt contiguous)
    hipMemsetAsync(val, 0, (size_t)2 * Bq * Pg * sizeof(float), stream);

    k_tables<<<48, 256, 0, stream>>>(T2c, T2s, T1e_g, A2_g);
    k_scatter<<<64, 64, 0, stream>>>(xyt, obs_c, obs_v, nb, siy, six, val, cnt);
    k_fc0<<<(Bq*Pg)/256, 256, 0, stream>>>(val, cnt, xg, yg, fc0w, fc0b, xh);

    for (int l = 0; l < 3; l++) {
        k_s12<<<Bq*Wd, 256, 0, stream>>>(xh, T1e_g, A2_g, xfr, xfi);
        k_s3<<<dim3(Bq, 24), 256, 0, stream>>>(xfr, xfi, w1r, w1i, w2r, w2i, ofr, ofi, l);
        k_s45<<<dim3(NXg, Bq), 256, 0, stream>>>(xh, ofr, ofi, T1e_g, T2c, T2s, pww, pwb, l);
    }
    // layer 3: forward transform + mode mix only; evaluate at 4 points in k_final
    k_s12<<<Bq*Wd, 256, 0, stream>>>(xh, T1e_g, A2_g, xfr, xfi);
    k_s3<<<dim3(Bq, 24), 256, 0, stream>>>(xfr, xfi, w1r, w1i, w2r, w2i, ofr, ofi, 3);
    k_final<<<Bq, 256, 0, stream>>>(xh, ofr, ofi, pww, pwb, fc1w, fc1b, fc2w, fc2b,
                                    xyt, Lx, Ly, out);
}